// Round 12
// baseline (203.823 us; speedup 1.0000x reference)
//
#include <hip/hip_runtime.h>

typedef unsigned short u16;
typedef unsigned int u32;
typedef __bf16 bf16x8 __attribute__((ext_vector_type(8)));
typedef float f32x4 __attribute__((ext_vector_type(4)));

#define DEV __device__ __forceinline__

// Problem constants (B,T,D_MODEL,H) = (2,2048,1024,16)
constexpr int BB = 2;
constexpr int TT = 2048;
constexpr int CD = 1024;
constexpr int HH = 16;
constexpr int DH = 64;
constexpr int BT = BB * TT;   // 4096

// softmax scale 1/8 folded with log2(e): S' = S/8*log2e, exp(x)=exp2(x')
#define QSCALE 0.18033688011112042f

DEV u16 f2bf(float f) {
    u32 u = __builtin_bit_cast(u32, f);
    u32 r = u + 0x7FFFu + ((u >> 16) & 1u);
    return (u16)(r >> 16);
}

DEV f32x4 mfma16(bf16x8 a, bf16x8 b, f32x4 c) {
    return __builtin_amdgcn_mfma_f32_16x16x32_bf16(a, b, c, 0, 0, 0);
}

// Async global->LDS, 16B per lane: LDS dest = wave-uniform base + lane*16.
DEV void gld_lds16(u16* lds, const u16* g) {
    __builtin_amdgcn_global_load_lds(
        (const __attribute__((address_space(1))) unsigned int*)g,
        (__attribute__((address_space(3))) unsigned int*)lds, 16, 0, 0);
}

// ---------------------------------------------------------------------------
// Fused preprocessing (single launch):
//   blocks [0,2048):      x fp32 -> bf16           (4096x1024)
//   blocks [2048,5120):   W_qkv (1024x3072) -> transposed bf16 (3072x1024)
//   blocks [5120,6144):   W_o   (1024x1024) -> transposed bf16 (1024x1024)
// ---------------------------------------------------------------------------
__global__ __launch_bounds__(256)
void prep_kernel(const float* __restrict__ x, u16* __restrict__ xb,
                 const float* __restrict__ Wqkv, u16* __restrict__ WqkvT,
                 const float* __restrict__ Wo, u16* __restrict__ WoT) {
    const int tid = threadIdx.x;
    int blk = blockIdx.x;
    if (blk < 2048) {                       // convert job
        const int i = (blk * 256 + tid) * 8;
        float4 a = *(const float4*)&x[i];
        float4 b = *(const float4*)&x[i + 4];
        u16 t[8];
        t[0] = f2bf(a.x); t[1] = f2bf(a.y); t[2] = f2bf(a.z); t[3] = f2bf(a.w);
        t[4] = f2bf(b.x); t[5] = f2bf(b.y); t[6] = f2bf(b.z); t[7] = f2bf(b.w);
        *(uint4*)&xb[i] = *(const uint4*)t;
        return;                             // whole block exits (no barrier)
    }
    __shared__ u16 tile[32][33];
    const float* in; u16* out; int rows, cols, bx, by;
    if (blk < 5120) { blk -= 2048; in = Wqkv; out = WqkvT; rows = 1024; cols = 3072; bx = blk % 96; by = blk / 96; }
    else            { blk -= 5120; in = Wo;   out = WoT;   rows = 1024; cols = 1024; bx = blk % 32; by = blk / 32; }
    const int c0 = bx * 32, r0 = by * 32;
    const int tx = tid & 31, ty = tid >> 5;
    #pragma unroll
    for (int i = ty; i < 32; i += 8)
        tile[i][tx] = f2bf(in[(r0 + i) * cols + (c0 + tx)]);
    __syncthreads();
    #pragma unroll
    for (int i = ty; i < 32; i += 8)
        out[(c0 + i) * rows + (r0 + tx)] = tile[tx][i];
}

// ---------------------------------------------------------------------------
// GEMM (r9-proven BK=32 structure): C[M][N] = A[M][K] * Bt[N][K]^T.
// BM=128, BN template (128 or 64), global_load_lds width-16 staging.
// r12: XCD-aware block swizzle — bid%8 = XCD; each XCD owns gridDim.x/8
// consecutive N-tiles (B-slice stays resident in its 4 MiB L2) while M
// sweeps.  Pure bijection on blocks: correctness-invariant.
// EPI==0: fp32 store to outf.  EPI==1: QKV scatter (bf16 Q,K,V^T); Q is
// pre-scaled by QSCALE (softmax scale + log2e folded in).
// ---------------------------------------------------------------------------
template <int EPI, int BN>
__global__ __launch_bounds__(256)
void gemm_bt(const u16* __restrict__ A, const u16* __restrict__ Bt,
             u16* __restrict__ out0, u16* __restrict__ out1,
             u16* __restrict__ out2, float* __restrict__ outf,
             int M, int N, int K) {
    constexpr int BM = 128, BK = 32, AST = 32;
    constexpr int NT = BN / 32;             // n-tiles per wave
    __shared__ alignas(16) u16 As[BM * AST];
    __shared__ alignas(16) u16 Bs[BN * AST];

    const int tid  = threadIdx.x;
    const int wave = tid >> 6, lane = tid & 63;
    const int quad = lane >> 4, l16 = lane & 15;
    const int wm = (wave & 1) * 64, wn = (wave >> 1) * (BN / 2);

    // XCD-aware swizzle (bijective): xcd = bid&7 -> N-range, m sweeps inside.
    const int nper = gridDim.x >> 3;
    const int bid  = blockIdx.y * gridDim.x + blockIdx.x;
    const int xcd  = bid & 7, slot = bid >> 3;
    const int bx   = xcd * nper + slot % nper;
    const int by   = slot / nper;
    const int m0 = by * BM, n0 = bx * BN;

    // DMA staging: one instr = 64 lanes x 16B = 16 rows x 64 B.
    const int srowA = wave * 32 + (lane >> 2);
    const int srowB = wave * (BN / 4) + (lane >> 2);
    const int scol  = (lane & 3) * 8;
    const u16* ga0 = A  + (size_t)(m0 + srowA) * K + scol;
    const u16* ga1 = ga0 + (size_t)16 * K;
    const u16* gb0 = Bt + (size_t)(n0 + srowB) * K + scol;
    const u16* gb1 = gb0 + (size_t)16 * K;
    u16* la0 = As + wave * 1024;
    u16* la1 = As + wave * 1024 + 512;
    u16* lb0 = Bs + wave * (BN * 8);
    u16* lb1 = Bs + wave * (BN * 8) + 512;

    f32x4 acc[4][NT] = {};

    for (int k0 = 0; k0 < K; k0 += BK) {
        gld_lds16(la0, ga0 + k0);
        gld_lds16(la1, ga1 + k0);
        gld_lds16(lb0, gb0 + k0);
        if constexpr (BN == 128) gld_lds16(lb1, gb1 + k0);
        __syncthreads();

        bf16x8 fa[4], fb[NT];
        #pragma unroll
        for (int mt = 0; mt < 4; ++mt)
            fa[mt] = *(const bf16x8*)&As[(wm + mt * 16 + l16) * AST + quad * 8];
        #pragma unroll
        for (int nt = 0; nt < NT; ++nt)
            fb[nt] = *(const bf16x8*)&Bs[(wn + nt * 16 + l16) * AST + quad * 8];
        #pragma unroll
        for (int mt = 0; mt < 4; ++mt)
            #pragma unroll
            for (int nt = 0; nt < NT; ++nt)
                acc[mt][nt] = mfma16(fa[mt], fb[nt], acc[mt][nt]);
        __syncthreads();
    }

    // Epilogue. C/D layout: row = quad*4+reg, col = l16.
    #pragma unroll
    for (int mt = 0; mt < 4; ++mt) {
        #pragma unroll
        for (int nt = 0; nt < NT; ++nt) {
            #pragma unroll
            for (int reg = 0; reg < 4; ++reg) {
                const int r = m0 + wm + mt * 16 + quad * 4 + reg;
                const int c = n0 + wn + nt * 16 + l16;
                if (EPI == 0) {
                    outf[(size_t)r * N + c] = acc[mt][nt][reg];
                } else {
                    const int which = c >> 10;       // 0=q 1=k 2=v
                    const int cc = c & 1023;
                    const int h = cc >> 6, d = cc & 63;
                    const int b = r >> 11, t = r & 2047;
                    const int bh = b * HH + h;
                    if (which == 0) {
                        out0[((size_t)bh * TT + t) * DH + d] =
                            f2bf(acc[mt][nt][reg] * QSCALE);
                    } else if (which == 1) {
                        out1[((size_t)bh * TT + t) * DH + d] = f2bf(acc[mt][nt][reg]);
                    } else {
                        out2[((size_t)bh * DH + d) * TT + t] = f2bf(acc[mt][nt][reg]);
                    }
                }
            }
        }
    }
}

// ---------------------------------------------------------------------------
// Flash attention v4 (causal): S^T formulation + paired-key full-K=32 PV.
// (unchanged from r9 — see r8/r9 notes)
// ---------------------------------------------------------------------------
constexpr int KST = 72;  // K/V LDS row stride (144 B, rows 16B-aligned)

DEV void attn_step(const bf16x8 fk[4][2], const bf16x8 fv[2][4],
                   const bf16x8* fq, f32x4* Oacc,
                   float& m_i, float& l_i, bool diag,
                   int wave, int quad, int l16) {
    // S^T: 4 key-tiles x 2 k-steps over d
    f32x4 st[4];
    #pragma unroll
    for (int nt = 0; nt < 4; ++nt) {
        f32x4 t = {};
        t = mfma16(fk[nt][0], fq[0], t);   // A=K (m=key), B=Q (n=q)
        t = mfma16(fk[nt][1], fq[1], t);
        st[nt] = t;
    }

    // causal mask on diagonal tile: key_loc <= q_loc
    if (diag) {
        const int qg = wave * 16 + l16;
        #pragma unroll
        for (int nt = 0; nt < 4; ++nt)
            #pragma unroll
            for (int reg = 0; reg < 4; ++reg) {
                const int kg = nt * 16 + quad * 4 + reg;
                st[nt][reg] = (kg <= qg) ? st[nt][reg] : -INFINITY;
            }
    }

    // row max: 15 in-register + 2 cross-quad shuffles
    float vmax = st[0][0];
    #pragma unroll
    for (int nt = 0; nt < 4; ++nt)
        #pragma unroll
        for (int reg = 0; reg < 4; ++reg)
            vmax = fmaxf(vmax, st[nt][reg]);
    vmax = fmaxf(vmax, __shfl_xor(vmax, 16, 64));
    vmax = fmaxf(vmax, __shfl_xor(vmax, 32, 64));

    const float mnew = fmaxf(m_i, vmax);
    const float alpha = __builtin_amdgcn_exp2f(m_i - mnew);
    m_i = mnew;

    float vsum = 0.f;
    #pragma unroll
    for (int nt = 0; nt < 4; ++nt)
        #pragma unroll
        for (int reg = 0; reg < 4; ++reg) {
            const float p = __builtin_amdgcn_exp2f(st[nt][reg] - mnew);
            st[nt][reg] = p;
            vsum += p;
        }
    vsum += __shfl_xor(vsum, 16, 64);
    vsum += __shfl_xor(vsum, 32, 64);
    l_i = l_i * alpha + vsum;

    #pragma unroll
    for (int dt = 0; dt < 4; ++dt)
        #pragma unroll
        for (int reg = 0; reg < 4; ++reg)
            Oacc[dt][reg] *= alpha;

    // P^T B-operand: reg j<4 = st[2p][j], reg j>=4 = st[2p+1][j-4]
    #pragma unroll
    for (int pair = 0; pair < 2; ++pair) {
        u16 pa[8];
        #pragma unroll
        for (int j = 0; j < 4; ++j) {
            pa[j]     = f2bf(st[2 * pair][j]);
            pa[4 + j] = f2bf(st[2 * pair + 1][j]);
        }
        const bf16x8 pb = *(const bf16x8*)pa;
        #pragma unroll
        for (int dt = 0; dt < 4; ++dt)
            Oacc[dt] = mfma16(fv[pair][dt], pb, Oacc[dt]);
    }
}

__global__ __launch_bounds__(256, 2)
void attn_kernel(const u16* __restrict__ Q, const u16* __restrict__ Kb,
                 const u16* __restrict__ Vt, u16* __restrict__ O) {
    __shared__ alignas(16) u16 Ks[2][64 * KST];
    __shared__ alignas(16) u16 Vs[2][64 * KST];

    const int p = blockIdx.x;         // 0..15
    const int bh = blockIdx.y;
    const int qtA = 31 - p;           // big tile; also jmax
    const int qtB = p;                // small tile
    const int jmax = qtA;

    const int tid = threadIdx.x;
    const int wave = tid >> 6, lane = tid & 63;
    const int quad = lane >> 4, l16 = lane & 15;

    const u16* Qh = Q  + (size_t)bh * TT * DH;
    const u16* Kh = Kb + (size_t)bh * TT * DH;
    const u16* Vh = Vt + (size_t)bh * DH * TT;

    const int rowA = qtA * 64 + wave * 16;
    const int rowB = qtB * 64 + wave * 16;

    // Q fragments (B-operand: n = l16 = q, k = quad*8+j over d)
    bf16x8 fqA[2], fqB[2];
    fqA[0] = *(const bf16x8*)&Qh[(rowA + l16) * DH + quad * 8];
    fqA[1] = *(const bf16x8*)&Qh[(rowA + l16) * DH + 32 + quad * 8];
    fqB[0] = *(const bf16x8*)&Qh[(rowB + l16) * DH + quad * 8];
    fqB[1] = *(const bf16x8*)&Qh[(rowB + l16) * DH + 32 + quad * 8];

    f32x4 OA[4] = {}, OB[4] = {};
    float mA = -INFINITY, lA = 0.f, mB = -INFINITY, lB = 0.f;

    // Chunk staging: thread i covers 16B at row (i>>3), col (i&7)*8, +row32.
    const int trow = tid >> 3;
    const int ic   = tid & 7;            // 8-key group index
    const int tcol = ic * 8;
    const int vc1 = 32 * (ic >> 2) + 16 * (ic & 1) + 4 * ((ic & 3) >> 1);
    uint4 kr0, kr1, vr0, vr1;

    auto load_chunk = [&](int j) {
        const u16* ks = Kh + (size_t)j * 64 * DH;
        kr0 = *(const uint4*)&ks[trow * DH + tcol];
        kr1 = *(const uint4*)&ks[(trow + 32) * DH + tcol];
        const u16* vs = Vh + (size_t)j * 64;
        vr0 = *(const uint4*)&vs[(size_t)trow * TT + tcol];
        vr1 = *(const uint4*)&vs[(size_t)(trow + 32) * TT + tcol];
    };
    auto write_chunk = [&](int buf) {
        *(uint4*)&Ks[buf][trow * KST + tcol]        = kr0;
        *(uint4*)&Ks[buf][(trow + 32) * KST + tcol] = kr1;
        *(uint2*)&Vs[buf][trow * KST + vc1]            = *(const uint2*)&vr0;
        *(uint2*)&Vs[buf][trow * KST + vc1 + 8]        = *((const uint2*)&vr0 + 1);
        *(uint2*)&Vs[buf][(trow + 32) * KST + vc1]     = *(const uint2*)&vr1;
        *(uint2*)&Vs[buf][(trow + 32) * KST + vc1 + 8] = *((const uint2*)&vr1 + 1);
    };

    load_chunk(0);
    write_chunk(0);

    for (int j = 0; j <= jmax; ++j) {
        const int cur = j & 1;
        __syncthreads();                    // buf[cur] staged & visible
        if (j < jmax) load_chunk(j + 1);    // loads fly during compute

        // Hoist K/V fragments once per chunk (shared by both q-tiles)
        bf16x8 fk[4][2], fv[2][4];
        #pragma unroll
        for (int nt = 0; nt < 4; ++nt) {
            fk[nt][0] = *(const bf16x8*)&Ks[cur][(nt * 16 + l16) * KST + quad * 8];
            fk[nt][1] = *(const bf16x8*)&Ks[cur][(nt * 16 + l16) * KST + 32 + quad * 8];
        }
        #pragma unroll
        for (int pair = 0; pair < 2; ++pair)
            #pragma unroll
            for (int dt = 0; dt < 4; ++dt)
                fv[pair][dt] = *(const bf16x8*)
                    &Vs[cur][(dt * 16 + l16) * KST + pair * 32 + quad * 8];

        attn_step(fk, fv, fqA, OA, mA, lA, (j == qtA), wave, quad, l16);
        if (j <= qtB)
            attn_step(fk, fv, fqB, OB, mB, lB, (j == qtB), wave, quad, l16);
        if (j < jmax) write_chunk(cur ^ 1); // after all buf[cur^1] readers done
    }

    // Epilogue: O^T rows d = dt*16+quad*4+reg, col q = l16; write (B,T,C).
    const int b = bh >> 4, h = bh & 15;
    const float rA = 1.f / lA, rB = 1.f / lB;
    #pragma unroll
    for (int dt = 0; dt < 4; ++dt) {
        u16 oa[4], ob[4];
        #pragma unroll
        for (int reg = 0; reg < 4; ++reg) {
            oa[reg] = f2bf(OA[dt][reg] * rA);
            ob[reg] = f2bf(OB[dt][reg] * rB);
        }
        *(uint2*)&O[((size_t)(b * TT + rowA + l16)) * CD + h * DH + dt * 16 + quad * 4] =
            *(const uint2*)oa;
        *(uint2*)&O[((size_t)(b * TT + rowB + l16)) * CD + h * DH + dt * 16 + quad * 4] =
            *(const uint2*)ob;
    }
}

// ---------------------------------------------------------------------------
extern "C" void kernel_launch(void* const* d_in, const int* in_sizes, int n_in,
                              void* d_out, int out_size, void* d_ws, size_t ws_size,
                              hipStream_t stream) {
    (void)in_sizes; (void)n_in; (void)out_size; (void)ws_size;
    const float* x    = (const float*)d_in[0];   // (4096, 1024) fp32
    const float* Wqkv = (const float*)d_in[1];   // (1024, 3072) fp32
    const float* Wo   = (const float*)d_in[2];   // (1024, 1024) fp32
    float* out = (float*)d_out;                  // (4096, 1024) fp32

    char* ws = (char*)d_ws;
    u16* xb    = (u16*)(ws + 0);                    // 4096x1024  (8 MB)
    u16* WqkvT = (u16*)(ws + (8u  << 20));          // 3072x1024  (6 MB)
    u16* WoT   = (u16*)(ws + (14u << 20));          // 1024x1024  (2 MB)
    u16* Qb    = (u16*)(ws + (16u << 20));          // (B,H,T,64) (8 MB)
    u16* Kb    = (u16*)(ws + (24u << 20));          // (B,H,T,64) (8 MB)
    u16* Vt    = (u16*)(ws + (32u << 20));          // (B,H,64,T) (8 MB)
    u16* attn  = (u16*)(ws + (40u << 20));          // (B,T,C)    (8 MB)

    prep_kernel<<<6144, 256, 0, stream>>>(x, xb, Wqkv, WqkvT, Wo, WoT);

    // qkv = x @ W_qkv, scattered to Q (pre-scaled) / K (B,H,T,64), V^T (B,H,64,T)
    gemm_bt<1, 128><<<dim3(3072 / 128, BT / 128), 256, 0, stream>>>(
        xb, WqkvT, Qb, Kb, Vt, nullptr, BT, 3072, CD);

    attn_kernel<<<dim3(16, BB * HH), 256, 0, stream>>>(Qb, Kb, Vt, attn);

    // out = attn @ W_o  (fp32 store to d_out); BN=64 -> 512 blocks = 2/CU
    gemm_bt<0, 64><<<dim3(CD / 64, BT / 128), 256, 0, stream>>>(
        attn, WoT, nullptr, nullptr, nullptr, out, BT, CD, CD);
}

// Round 13
// 191.920 us; speedup vs baseline: 1.0620x; 1.0620x over previous
//
#include <hip/hip_runtime.h>

typedef unsigned short u16;
typedef unsigned int u32;
typedef __bf16 bf16x8 __attribute__((ext_vector_type(8)));
typedef float f32x4 __attribute__((ext_vector_type(4)));

#define DEV __device__ __forceinline__

// Problem constants (B,T,D_MODEL,H) = (2,2048,1024,16)
constexpr int BB = 2;
constexpr int TT = 2048;
constexpr int CD = 1024;
constexpr int HH = 16;
constexpr int DH = 64;
constexpr int BT = BB * TT;   // 4096

// softmax scale 1/8 folded with log2(e): S' = S/8*log2e, exp(x)=exp2(x')
#define QSCALE 0.18033688011112042f

DEV u16 f2bf(float f) {
    u32 u = __builtin_bit_cast(u32, f);
    u32 r = u + 0x7FFFu + ((u >> 16) & 1u);
    return (u16)(r >> 16);
}

// Pack two fp32 -> packed bf16x2 (RNE), via v_perm_b32: 3 VALU per pair.
// perm sel 0x07060302: dst = hi16(s0)<<16 | hi16(s1)  (s0=hi elem, s1=lo elem)
DEV u32 packbf2(float lo, float hi) {
    u32 a = __builtin_bit_cast(u32, lo);
    u32 b = __builtin_bit_cast(u32, hi);
    a += 0x7FFFu + ((a >> 16) & 1u);
    b += 0x7FFFu + ((b >> 16) & 1u);
    return __builtin_amdgcn_perm(b, a, 0x07060302);
}

DEV f32x4 mfma16(bf16x8 a, bf16x8 b, f32x4 c) {
    return __builtin_amdgcn_mfma_f32_16x16x32_bf16(a, b, c, 0, 0, 0);
}

// Async global->LDS, 16B per lane: LDS dest = wave-uniform base + lane*16.
DEV void gld_lds16(u16* lds, const u16* g) {
    __builtin_amdgcn_global_load_lds(
        (const __attribute__((address_space(1))) unsigned int*)g,
        (__attribute__((address_space(3))) unsigned int*)lds, 16, 0, 0);
}

// ---------------------------------------------------------------------------
// Fused preprocessing (single launch):
//   blocks [0,2048):      x fp32 -> bf16           (4096x1024)
//   blocks [2048,5120):   W_qkv (1024x3072) -> transposed bf16 (3072x1024)
//   blocks [5120,6144):   W_o   (1024x1024) -> transposed bf16 (1024x1024)
// ---------------------------------------------------------------------------
__global__ __launch_bounds__(256)
void prep_kernel(const float* __restrict__ x, u16* __restrict__ xb,
                 const float* __restrict__ Wqkv, u16* __restrict__ WqkvT,
                 const float* __restrict__ Wo, u16* __restrict__ WoT) {
    const int tid = threadIdx.x;
    int blk = blockIdx.x;
    if (blk < 2048) {                       // convert job
        const int i = (blk * 256 + tid) * 8;
        float4 a = *(const float4*)&x[i];
        float4 b = *(const float4*)&x[i + 4];
        u16 t[8];
        t[0] = f2bf(a.x); t[1] = f2bf(a.y); t[2] = f2bf(a.z); t[3] = f2bf(a.w);
        t[4] = f2bf(b.x); t[5] = f2bf(b.y); t[6] = f2bf(b.z); t[7] = f2bf(b.w);
        *(uint4*)&xb[i] = *(const uint4*)t;
        return;                             // whole block exits (no barrier)
    }
    __shared__ u16 tile[32][33];
    const float* in; u16* out; int rows, cols, bx, by;
    if (blk < 5120) { blk -= 2048; in = Wqkv; out = WqkvT; rows = 1024; cols = 3072; bx = blk % 96; by = blk / 96; }
    else            { blk -= 5120; in = Wo;   out = WoT;   rows = 1024; cols = 1024; bx = blk % 32; by = blk / 32; }
    const int c0 = bx * 32, r0 = by * 32;
    const int tx = tid & 31, ty = tid >> 5;
    #pragma unroll
    for (int i = ty; i < 32; i += 8)
        tile[i][tx] = f2bf(in[(r0 + i) * cols + (c0 + tx)]);
    __syncthreads();
    #pragma unroll
    for (int i = ty; i < 32; i += 8)
        out[(c0 + i) * rows + (r0 + tx)] = tile[tx][i];
}

// ---------------------------------------------------------------------------
// GEMM (r9-proven BK=32 structure, natural dispatch order — r11's BK=64 and
// r12's XCD swizzle both measured as regressions; this config is the local
// optimum): C[M][N] = A[M][K] * Bt[N][K]^T.
// BM=128, BN template (128 or 64), global_load_lds width-16 staging.
// EPI==0: fp32 store to outf.  EPI==1: QKV scatter (bf16 Q,K,V^T); Q is
// pre-scaled by QSCALE (softmax scale + log2e folded in).
// ---------------------------------------------------------------------------
template <int EPI, int BN>
__global__ __launch_bounds__(256)
void gemm_bt(const u16* __restrict__ A, const u16* __restrict__ Bt,
             u16* __restrict__ out0, u16* __restrict__ out1,
             u16* __restrict__ out2, float* __restrict__ outf,
             int M, int N, int K) {
    constexpr int BM = 128, BK = 32, AST = 32;
    constexpr int NT = BN / 32;             // n-tiles per wave
    __shared__ alignas(16) u16 As[BM * AST];
    __shared__ alignas(16) u16 Bs[BN * AST];

    const int tid  = threadIdx.x;
    const int wave = tid >> 6, lane = tid & 63;
    const int quad = lane >> 4, l16 = lane & 15;
    const int wm = (wave & 1) * 64, wn = (wave >> 1) * (BN / 2);
    const int m0 = blockIdx.y * BM, n0 = blockIdx.x * BN;

    // DMA staging: one instr = 64 lanes x 16B = 16 rows x 64 B.
    const int srowA = wave * 32 + (lane >> 2);
    const int srowB = wave * (BN / 4) + (lane >> 2);
    const int scol  = (lane & 3) * 8;
    const u16* ga0 = A  + (size_t)(m0 + srowA) * K + scol;
    const u16* ga1 = ga0 + (size_t)16 * K;
    const u16* gb0 = Bt + (size_t)(n0 + srowB) * K + scol;
    const u16* gb1 = gb0 + (size_t)16 * K;
    u16* la0 = As + wave * 1024;
    u16* la1 = As + wave * 1024 + 512;
    u16* lb0 = Bs + wave * (BN * 8);
    u16* lb1 = Bs + wave * (BN * 8) + 512;

    f32x4 acc[4][NT] = {};

    for (int k0 = 0; k0 < K; k0 += BK) {
        gld_lds16(la0, ga0 + k0);
        gld_lds16(la1, ga1 + k0);
        gld_lds16(lb0, gb0 + k0);
        if constexpr (BN == 128) gld_lds16(lb1, gb1 + k0);
        __syncthreads();

        bf16x8 fa[4], fb[NT];
        #pragma unroll
        for (int mt = 0; mt < 4; ++mt)
            fa[mt] = *(const bf16x8*)&As[(wm + mt * 16 + l16) * AST + quad * 8];
        #pragma unroll
        for (int nt = 0; nt < NT; ++nt)
            fb[nt] = *(const bf16x8*)&Bs[(wn + nt * 16 + l16) * AST + quad * 8];
        #pragma unroll
        for (int mt = 0; mt < 4; ++mt)
            #pragma unroll
            for (int nt = 0; nt < NT; ++nt)
                acc[mt][nt] = mfma16(fa[mt], fb[nt], acc[mt][nt]);
        __syncthreads();
    }

    // Epilogue. C/D layout: row = quad*4+reg, col = l16.
    #pragma unroll
    for (int mt = 0; mt < 4; ++mt) {
        #pragma unroll
        for (int nt = 0; nt < NT; ++nt) {
            #pragma unroll
            for (int reg = 0; reg < 4; ++reg) {
                const int r = m0 + wm + mt * 16 + quad * 4 + reg;
                const int c = n0 + wn + nt * 16 + l16;
                if (EPI == 0) {
                    outf[(size_t)r * N + c] = acc[mt][nt][reg];
                } else {
                    const int which = c >> 10;       // 0=q 1=k 2=v
                    const int cc = c & 1023;
                    const int h = cc >> 6, d = cc & 63;
                    const int b = r >> 11, t = r & 2047;
                    const int bh = b * HH + h;
                    if (which == 0) {
                        out0[((size_t)bh * TT + t) * DH + d] =
                            f2bf(acc[mt][nt][reg] * QSCALE);
                    } else if (which == 1) {
                        out1[((size_t)bh * TT + t) * DH + d] = f2bf(acc[mt][nt][reg]);
                    } else {
                        out2[((size_t)bh * DH + d) * TT + t] = f2bf(acc[mt][nt][reg]);
                    }
                }
            }
        }
    }
}

// ---------------------------------------------------------------------------
// Flash attention v4 (causal): S^T formulation + paired-key full-K=32 PV.
// r13: P^T pack via v_perm_b32 (packbf2) — same RNE numerics, ~2.3x fewer
// VALU ops in the hot pack (attn was 48% VALUBusy at r8 profiling).
// ---------------------------------------------------------------------------
constexpr int KST = 72;  // K/V LDS row stride (144 B, rows 16B-aligned)

DEV void attn_step(const bf16x8 fk[4][2], const bf16x8 fv[2][4],
                   const bf16x8* fq, f32x4* Oacc,
                   float& m_i, float& l_i, bool diag,
                   int wave, int quad, int l16) {
    // S^T: 4 key-tiles x 2 k-steps over d
    f32x4 st[4];
    #pragma unroll
    for (int nt = 0; nt < 4; ++nt) {
        f32x4 t = {};
        t = mfma16(fk[nt][0], fq[0], t);   // A=K (m=key), B=Q (n=q)
        t = mfma16(fk[nt][1], fq[1], t);
        st[nt] = t;
    }

    // causal mask on diagonal tile: key_loc <= q_loc
    if (diag) {
        const int qg = wave * 16 + l16;
        #pragma unroll
        for (int nt = 0; nt < 4; ++nt)
            #pragma unroll
            for (int reg = 0; reg < 4; ++reg) {
                const int kg = nt * 16 + quad * 4 + reg;
                st[nt][reg] = (kg <= qg) ? st[nt][reg] : -INFINITY;
            }
    }

    // row max: 15 in-register + 2 cross-quad shuffles
    float vmax = st[0][0];
    #pragma unroll
    for (int nt = 0; nt < 4; ++nt)
        #pragma unroll
        for (int reg = 0; reg < 4; ++reg)
            vmax = fmaxf(vmax, st[nt][reg]);
    vmax = fmaxf(vmax, __shfl_xor(vmax, 16, 64));
    vmax = fmaxf(vmax, __shfl_xor(vmax, 32, 64));

    const float mnew = fmaxf(m_i, vmax);
    const float alpha = __builtin_amdgcn_exp2f(m_i - mnew);
    m_i = mnew;

    float vsum = 0.f;
    #pragma unroll
    for (int nt = 0; nt < 4; ++nt)
        #pragma unroll
        for (int reg = 0; reg < 4; ++reg) {
            const float p = __builtin_amdgcn_exp2f(st[nt][reg] - mnew);
            st[nt][reg] = p;
            vsum += p;
        }
    vsum += __shfl_xor(vsum, 16, 64);
    vsum += __shfl_xor(vsum, 32, 64);
    l_i = l_i * alpha + vsum;

    #pragma unroll
    for (int dt = 0; dt < 4; ++dt)
        #pragma unroll
        for (int reg = 0; reg < 4; ++reg)
            Oacc[dt][reg] *= alpha;

    // P^T B-operand: elems j<4 = st[2p][j] (key p*32+quad*4+j),
    //                elems j>=4 = st[2p+1][j-4].  Packed via v_perm (RNE).
    #pragma unroll
    for (int pair = 0; pair < 2; ++pair) {
        u32 pw[4];
        pw[0] = packbf2(st[2 * pair][0],     st[2 * pair][1]);
        pw[1] = packbf2(st[2 * pair][2],     st[2 * pair][3]);
        pw[2] = packbf2(st[2 * pair + 1][0], st[2 * pair + 1][1]);
        pw[3] = packbf2(st[2 * pair + 1][2], st[2 * pair + 1][3]);
        bf16x8 pb;
        __builtin_memcpy(&pb, pw, 16);
        #pragma unroll
        for (int dt = 0; dt < 4; ++dt)
            Oacc[dt] = mfma16(fv[pair][dt], pb, Oacc[dt]);
    }
}

__global__ __launch_bounds__(256, 2)
void attn_kernel(const u16* __restrict__ Q, const u16* __restrict__ Kb,
                 const u16* __restrict__ Vt, u16* __restrict__ O) {
    __shared__ alignas(16) u16 Ks[2][64 * KST];
    __shared__ alignas(16) u16 Vs[2][64 * KST];

    const int p = blockIdx.x;         // 0..15
    const int bh = blockIdx.y;
    const int qtA = 31 - p;           // big tile; also jmax
    const int qtB = p;                // small tile
    const int jmax = qtA;

    const int tid = threadIdx.x;
    const int wave = tid >> 6, lane = tid & 63;
    const int quad = lane >> 4, l16 = lane & 15;

    const u16* Qh = Q  + (size_t)bh * TT * DH;
    const u16* Kh = Kb + (size_t)bh * TT * DH;
    const u16* Vh = Vt + (size_t)bh * DH * TT;

    const int rowA = qtA * 64 + wave * 16;
    const int rowB = qtB * 64 + wave * 16;

    // Q fragments (B-operand: n = l16 = q, k = quad*8+j over d)
    bf16x8 fqA[2], fqB[2];
    fqA[0] = *(const bf16x8*)&Qh[(rowA + l16) * DH + quad * 8];
    fqA[1] = *(const bf16x8*)&Qh[(rowA + l16) * DH + 32 + quad * 8];
    fqB[0] = *(const bf16x8*)&Qh[(rowB + l16) * DH + quad * 8];
    fqB[1] = *(const bf16x8*)&Qh[(rowB + l16) * DH + 32 + quad * 8];

    f32x4 OA[4] = {}, OB[4] = {};
    float mA = -INFINITY, lA = 0.f, mB = -INFINITY, lB = 0.f;

    // Chunk staging: thread i covers 16B at row (i>>3), col (i&7)*8, +row32.
    const int trow = tid >> 3;
    const int ic   = tid & 7;            // 8-key group index
    const int tcol = ic * 8;
    const int vc1 = 32 * (ic >> 2) + 16 * (ic & 1) + 4 * ((ic & 3) >> 1);
    uint4 kr0, kr1, vr0, vr1;

    auto load_chunk = [&](int j) {
        const u16* ks = Kh + (size_t)j * 64 * DH;
        kr0 = *(const uint4*)&ks[trow * DH + tcol];
        kr1 = *(const uint4*)&ks[(trow + 32) * DH + tcol];
        const u16* vs = Vh + (size_t)j * 64;
        vr0 = *(const uint4*)&vs[(size_t)trow * TT + tcol];
        vr1 = *(const uint4*)&vs[(size_t)(trow + 32) * TT + tcol];
    };
    auto write_chunk = [&](int buf) {
        *(uint4*)&Ks[buf][trow * KST + tcol]        = kr0;
        *(uint4*)&Ks[buf][(trow + 32) * KST + tcol] = kr1;
        *(uint2*)&Vs[buf][trow * KST + vc1]            = *(const uint2*)&vr0;
        *(uint2*)&Vs[buf][trow * KST + vc1 + 8]        = *((const uint2*)&vr0 + 1);
        *(uint2*)&Vs[buf][(trow + 32) * KST + vc1]     = *(const uint2*)&vr1;
        *(uint2*)&Vs[buf][(trow + 32) * KST + vc1 + 8] = *((const uint2*)&vr1 + 1);
    };

    load_chunk(0);
    write_chunk(0);

    for (int j = 0; j <= jmax; ++j) {
        const int cur = j & 1;
        __syncthreads();                    // buf[cur] staged & visible
        if (j < jmax) load_chunk(j + 1);    // loads fly during compute

        // Hoist K/V fragments once per chunk (shared by both q-tiles)
        bf16x8 fk[4][2], fv[2][4];
        #pragma unroll
        for (int nt = 0; nt < 4; ++nt) {
            fk[nt][0] = *(const bf16x8*)&Ks[cur][(nt * 16 + l16) * KST + quad * 8];
            fk[nt][1] = *(const bf16x8*)&Ks[cur][(nt * 16 + l16) * KST + 32 + quad * 8];
        }
        #pragma unroll
        for (int pair = 0; pair < 2; ++pair)
            #pragma unroll
            for (int dt = 0; dt < 4; ++dt)
                fv[pair][dt] = *(const bf16x8*)
                    &Vs[cur][(dt * 16 + l16) * KST + pair * 32 + quad * 8];

        attn_step(fk, fv, fqA, OA, mA, lA, (j == qtA), wave, quad, l16);
        if (j <= qtB)
            attn_step(fk, fv, fqB, OB, mB, lB, (j == qtB), wave, quad, l16);
        if (j < jmax) write_chunk(cur ^ 1); // after all buf[cur^1] readers done
    }

    // Epilogue: O^T rows d = dt*16+quad*4+reg, col q = l16; write (B,T,C).
    const int b = bh >> 4, h = bh & 15;
    const float rA = 1.f / lA, rB = 1.f / lB;
    #pragma unroll
    for (int dt = 0; dt < 4; ++dt) {
        u16 oa[4], ob[4];
        #pragma unroll
        for (int reg = 0; reg < 4; ++reg) {
            oa[reg] = f2bf(OA[dt][reg] * rA);
            ob[reg] = f2bf(OB[dt][reg] * rB);
        }
        *(uint2*)&O[((size_t)(b * TT + rowA + l16)) * CD + h * DH + dt * 16 + quad * 4] =
            *(const uint2*)oa;
        *(uint2*)&O[((size_t)(b * TT + rowB + l16)) * CD + h * DH + dt * 16 + quad * 4] =
            *(const uint2*)ob;
    }
}

// ---------------------------------------------------------------------------
extern "C" void kernel_launch(void* const* d_in, const int* in_sizes, int n_in,
                              void* d_out, int out_size, void* d_ws, size_t ws_size,
                              hipStream_t stream) {
    (void)in_sizes; (void)n_in; (void)out_size; (void)ws_size;
    const float* x    = (const float*)d_in[0];   // (4096, 1024) fp32
    const float* Wqkv = (const float*)d_in[1];   // (1024, 3072) fp32
    const float* Wo   = (const float*)d_in[2];   // (1024, 1024) fp32
    float* out = (float*)d_out;                  // (4096, 1024) fp32

    char* ws = (char*)d_ws;
    u16* xb    = (u16*)(ws + 0);                    // 4096x1024  (8 MB)
    u16* WqkvT = (u16*)(ws + (8u  << 20));          // 3072x1024  (6 MB)
    u16* WoT   = (u16*)(ws + (14u << 20));          // 1024x1024  (2 MB)
    u16* Qb    = (u16*)(ws + (16u << 20));          // (B,H,T,64) (8 MB)
    u16* Kb    = (u16*)(ws + (24u << 20));          // (B,H,T,64) (8 MB)
    u16* Vt    = (u16*)(ws + (32u << 20));          // (B,H,64,T) (8 MB)
    u16* attn  = (u16*)(ws + (40u << 20));          // (B,T,C)    (8 MB)

    prep_kernel<<<6144, 256, 0, stream>>>(x, xb, Wqkv, WqkvT, Wo, WoT);

    // qkv = x @ W_qkv, scattered to Q (pre-scaled) / K (B,H,T,64), V^T (B,H,64,T)
    gemm_bt<1, 128><<<dim3(3072 / 128, BT / 128), 256, 0, stream>>>(
        xb, WqkvT, Qb, Kb, Vt, nullptr, BT, 3072, CD);

    attn_kernel<<<dim3(16, BB * HH), 256, 0, stream>>>(Qb, Kb, Vt, attn);

    // out = attn @ W_o  (fp32 store to d_out); BN=64 -> 512 blocks = 2/CU
    gemm_bt<0, 64><<<dim3(CD / 64, BT / 128), 256, 0, stream>>>(
        attn, WoT, nullptr, nullptr, nullptr, out, BT, CD, CD);
}